// Round 1
// baseline (1593.451 us; speedup 1.0000x reference)
//
#include <hip/hip_runtime.h>

// Problem constants (DAG_61246233641129)
#define IN_SIZE 1024
#define N_NODES 4224
#define TOTAL   5248   // IN_SIZE + N_NODES
#define BATCH   512
#define OUTSZ   128
#define NB      128    // node block size
#define NBLK    33     // N_NODES / NB

// fast tanh: tanh(x) = 1 - 2/(exp2(2x*log2e)+1). abs err ~1e-6, monotone, saturates correctly.
__device__ __forceinline__ float fast_tanh(float x) {
  float e = __builtin_amdgcn_exp2f(x * 2.885390081777927f); // 2*log2(e)
  return 1.0f - 2.0f * __builtin_amdgcn_rcpf(e + 1.0f);
}

// G[i][b] = x[b][i] for i < IN_SIZE  (parent-major, batch-contiguous layout)
__global__ void transpose_x(const float* __restrict__ x, float* __restrict__ G) {
  __shared__ float tile[32][33];
  int tx = threadIdx.x & 31, ty = threadIdx.x >> 5; // 32 x 8
  int i0 = blockIdx.x * 32, b0 = blockIdx.y * 32;
#pragma unroll
  for (int q = 0; q < 4; q++) {
    int b = ty + q * 8;
    tile[b][tx] = x[(size_t)(b0 + b) * IN_SIZE + i0 + tx]; // coalesced along i
  }
  __syncthreads();
#pragma unroll
  for (int q = 0; q < 4; q++) {
    int i = ty + q * 8;
    G[(size_t)(i0 + i) * BATCH + b0 + tx] = tile[tx][i];   // coalesced along b
  }
}

// C[j][b] (+)= sum_{i in [i0, i0+ilen)} W[j][i] * G[i][b]
// grid.x = j-tiles (128 wide, starting at j0), grid.y = 4 b-tiles (128 wide). 256 threads.
__global__ void gemm_cacc(const float* __restrict__ W, const float* __restrict__ G,
                          float* __restrict__ C, int i0, int ilen, int j0, int init) {
  __shared__ float Wl[16][128]; // Wl[kk][j]
  __shared__ float Gl[16][128]; // Gl[kk][b]
  int t = threadIdx.x;
  int jbase = j0 + blockIdx.x * 128, bbase = blockIdx.y * 128;
  int tb = t & 15, tj = t >> 4; // consecutive lanes -> consecutive b (coalesced epilogue)
  float acc[8][8];
#pragma unroll
  for (int a = 0; a < 8; a++)
#pragma unroll
    for (int c = 0; c < 8; c++) acc[a][c] = 0.0f;

  int sj = t & 127, sh = t >> 7;        // W staging: 128 j x (2 k-halves of 8)
  int gk = t >> 4, gb = (t & 15) * 8;   // G staging: 16 k x 128 b

  for (int k = 0; k < ilen; k += 16) {
    __syncthreads();
    {
      const float* wr = W + (size_t)(jbase + sj) * TOTAL + i0 + k + sh * 8;
      float4 v0 = *(const float4*)wr;
      float4 v1 = *(const float4*)(wr + 4);
      int kk = sh * 8;
      Wl[kk + 0][sj] = v0.x; Wl[kk + 1][sj] = v0.y; Wl[kk + 2][sj] = v0.z; Wl[kk + 3][sj] = v0.w;
      Wl[kk + 4][sj] = v1.x; Wl[kk + 5][sj] = v1.y; Wl[kk + 6][sj] = v1.z; Wl[kk + 7][sj] = v1.w;
    }
    {
      const float* gr = G + (size_t)(i0 + k + gk) * BATCH + bbase + gb;
      float4 v0 = *(const float4*)gr;
      float4 v1 = *(const float4*)(gr + 4);
      *(float4*)&Gl[gk][gb] = v0;
      *(float4*)&Gl[gk][gb + 4] = v1;
    }
    __syncthreads();
#pragma unroll
    for (int kk = 0; kk < 16; kk++) {
      float wv[8], gv[8];
      *(float4*)&wv[0] = *(const float4*)&Wl[kk][tj * 8];
      *(float4*)&wv[4] = *(const float4*)&Wl[kk][tj * 8 + 4];
      *(float4*)&gv[0] = *(const float4*)&Gl[kk][tb * 8];
      *(float4*)&gv[4] = *(const float4*)&Gl[kk][tb * 8 + 4];
#pragma unroll
      for (int a = 0; a < 8; a++)
#pragma unroll
        for (int c = 0; c < 8; c++) acc[a][c] += wv[a] * gv[c];
    }
  }
#pragma unroll
  for (int a = 0; a < 8; a++) {
    float* cr = C + (size_t)(jbase + tj * 8 + a) * BATCH + bbase + tb * 8;
    if (init) {
      *(float4*)cr       = make_float4(acc[a][0], acc[a][1], acc[a][2], acc[a][3]);
      *(float4*)(cr + 4) = make_float4(acc[a][4], acc[a][5], acc[a][6], acc[a][7]);
    } else {
      float4 o0 = *(const float4*)cr, o1 = *(const float4*)(cr + 4);
      o0.x += acc[a][0]; o0.y += acc[a][1]; o0.z += acc[a][2]; o0.w += acc[a][3];
      o1.x += acc[a][4]; o1.y += acc[a][5]; o1.z += acc[a][6]; o1.w += acc[a][7];
      *(float4*)cr = o0; *(float4*)(cr + 4) = o1;
    }
  }
}

// Sequential solve of one 128-node diagonal block for all 512 batch chains.
// 16 WGs x 256 threads; 8 lanes per batch element (t&7), 32 batches per WG.
// Lane l owns the 16 target nodes j_local in [16l, 16l+16) (scatter-form accumulators).
// Per step i: broadcast owner's acc via shfl, all lanes compute tanh redundantly
// (uniform, no divergence), then scatter h*W into owned future accumulators.
__global__ void solve_block(const float* __restrict__ W, float* __restrict__ G,
                            const float* __restrict__ C, int kblk) {
  __shared__ float Wt[NB][NB]; // Wt[i][swz(j)] = W[j0+j][IN_SIZE+j0+i], column-swizzled
  int j0 = kblk * NB;
  int t = threadIdx.x;
  int l = t & 7, g = t >> 3;
  int b = blockIdx.x * 32 + g;

  // stage + transpose the diagonal weight block, swizzling columns to spread banks
  {
    int j = t & 127, half = t >> 7;
    int pj = j ^ (((j >> 5) & 3) << 2);
    const float* wr = W + (size_t)(j0 + j) * TOTAL + IN_SIZE + j0 + half * 64;
#pragma unroll
    for (int q = 0; q < 64; q += 4) {
      float4 v = *(const float4*)(wr + q);
      int i = half * 64 + q;
      Wt[i + 0][pj] = v.x; Wt[i + 1][pj] = v.y; Wt[i + 2][pj] = v.z; Wt[i + 3][pj] = v.w;
    }
  }
  __syncthreads();

  float acc[16], hown[16];
  {
    const float* cb = C + (size_t)(j0 + l * 16) * BATCH + b;
#pragma unroll
    for (int m = 0; m < 16; m++) acc[m] = cb[(size_t)m * BATCH];
  }

  for (int r = 0; r < 8; r++) {
#pragma unroll
    for (int jj = 0; jj < 16; jj++) {
      int i = r * 16 + jj;
      float s = __shfl(acc[jj], r, 8);  // owner lane r's accumulator for node i
      float h = fast_tanh(s);
      if (l == r) hown[jj] = h;
      const float* wrow = &Wt[i][0];
#pragma unroll
      for (int c = 0; c < 4; c++) {
        int col = l * 16 + c * 4;
        int pc = col ^ (((col >> 5) & 3) << 2);
        float4 wv = *(const float4*)(wrow + pc);
        // dead accumulators (already-solved nodes) absorb harmless garbage;
        // live (future) accumulators get the correct h_i * W[j][i] contribution.
        acc[c * 4 + 0] += h * wv.x;
        acc[c * 4 + 1] += h * wv.y;
        acc[c * 4 + 2] += h * wv.z;
        acc[c * 4 + 3] += h * wv.w;
      }
    }
  }
  {
    float* gh = G + (size_t)(IN_SIZE + j0 + l * 16) * BATCH + b;
#pragma unroll
    for (int m = 0; m < 16; m++) gh[(size_t)m * BATCH] = hown[m];
  }
}

// out[b][o] = sigmoid(h[4096+o][b])
__global__ void out_sigmoid(const float* __restrict__ G, float* __restrict__ out) {
  int idx = blockIdx.x * 256 + threadIdx.x; // 65536 total
  int o = idx & 127, b = idx >> 7;
  float v = G[(size_t)(IN_SIZE + N_NODES - OUTSZ + o) * BATCH + b];
  out[(size_t)b * OUTSZ + o] =
      __builtin_amdgcn_rcpf(1.0f + __builtin_amdgcn_exp2f(-v * 1.4426950408889634f));
}

extern "C" void kernel_launch(void* const* d_in, const int* in_sizes, int n_in,
                              void* d_out, int out_size, void* d_ws, size_t ws_size,
                              hipStream_t stream) {
  const float* x = (const float*)d_in[0];
  const float* W = (const float*)d_in[1];
  float* out = (float*)d_out;
  // workspace: G[TOTAL][BATCH] then C[N_NODES][BATCH]  (~18.5 MB total)
  float* G = (float*)d_ws;
  float* C = G + (size_t)TOTAL * BATCH;

  hipLaunchKernelGGL(transpose_x, dim3(32, 16), dim3(256), 0, stream, x, G);
  // C init: input GEMM over all 33 j-blocks
  hipLaunchKernelGGL(gemm_cacc, dim3(NBLK, 4), dim3(256), 0, stream,
                     W, G, C, 0, IN_SIZE, 0, 1);
  for (int k = 0; k < NBLK; k++) {
    hipLaunchKernelGGL(solve_block, dim3(16), dim3(256), 0, stream, W, G, C, k);
    if (k < NBLK - 1) {
      // scatter block k's h into all future C columns (blocks k+1..32)
      hipLaunchKernelGGL(gemm_cacc, dim3(NBLK - 1 - k, 4), dim3(256), 0, stream,
                         W, G, C, IN_SIZE + k * NB, NB, (k + 1) * NB, 0);
    }
  }
  hipLaunchKernelGGL(out_sigmoid, dim3(256), dim3(256), 0, stream, G, out);
}

// Round 2
// 1374.359 us; speedup vs baseline: 1.1594x; 1.1594x over previous
//
#include <hip/hip_runtime.h>
#include <hip/hip_bf16.h>

// Problem constants (DAG_61246233641129)
#define IN_SIZE 1024
#define N_NODES 4224
#define TOTAL   5248   // IN_SIZE + N_NODES
#define BATCH   512
#define OUTSZ   128
#define NB      128    // node block size
#define NBLK    33     // N_NODES / NB

typedef __attribute__((ext_vector_type(8))) short short8;
typedef __attribute__((ext_vector_type(4))) float f32x4;

// fast tanh: tanh(x) = 1 - 2/(exp2(2x*log2e)+1). abs err ~1e-6, monotone, saturates.
__device__ __forceinline__ float fast_tanh(float x) {
  float e = __builtin_amdgcn_exp2f(x * 2.885390081777927f); // 2*log2(e)
  return 1.0f - 2.0f * __builtin_amdgcn_rcpf(e + 1.0f);
}

// pack two f32 -> two bf16 (RNE) in one u32 (compiler emits v_cvt_pk_bf16_f32)
__device__ __forceinline__ unsigned pack2(float a, float b) {
  __hip_bfloat162 h = __float22bfloat162_rn(float2{a, b});
  return *reinterpret_cast<unsigned*>(&h);
}

// Gt[b][i] = bf16(x[b][i]) for i < IN_SIZE (batch-major activation buffer)
__global__ void conv_x(const float* __restrict__ x, ushort* __restrict__ Gt) {
  int idx = blockIdx.x * 256 + threadIdx.x; // 65536 threads, 8 elems each
  int b = idx >> 7, i8 = (idx & 127) * 8;
  const float* p = x + (size_t)b * IN_SIZE + i8;
  float4 v0 = *(const float4*)p;
  float4 v1 = *(const float4*)(p + 4);
  uint4 o;
  o.x = pack2(v0.x, v0.y); o.y = pack2(v0.z, v0.w);
  o.z = pack2(v1.x, v1.y); o.w = pack2(v1.z, v1.w);
  *(uint4*)(Gt + (size_t)b * TOTAL + i8) = o;
}

// C[j][b] (+)= sum_{i in [i0, i0+ilen)} W[j][i] * Gt[b][i]   (bf16 MFMA, f32 accum)
// A = W rows (f32->bf16 converted during staging), B = Gt rows (bf16).
// BM=BN=128, BK=32. 256 threads = 4 waves in 2x2, wave tile 64x64 (4x4 frags 16x16x32).
// LDS tiles stored as [row][chunk16] with chunk ^= (row>>1)&3 swizzle -> 2-way max.
__global__ void gemm_bf16(const float* __restrict__ W, const ushort* __restrict__ Gt,
                          float* __restrict__ C, int i0, int ilen, int j0, int init) {
  __shared__ uint4 Al[128][4]; // 8 KB: W tile, bf16, swizzled chunks
  __shared__ uint4 Bl[128][4]; // 8 KB: Gt tile
  int t = threadIdx.x;
  int jbase = j0 + blockIdx.x * 128, bbase = blockIdx.y * 128;
  int w = t >> 6, l = t & 63;
  int wm = w >> 1, wn = w & 1;
  int rl = l & 15, kh = l >> 4;
  int rdc = kh ^ ((rl >> 1) & 3); // swizzled read chunk (same for all m/n: m*8&3==0)

  f32x4 acc[4][4];
#pragma unroll
  for (int m = 0; m < 4; m++)
#pragma unroll
    for (int n = 0; n < 4; n++) acc[m][n] = f32x4{0.f, 0.f, 0.f, 0.f};

  int srow = t >> 1, shalf = t & 1;        // staging: 2 threads/row, 16 elems each
  int ssw = (srow >> 1) & 3;
  const float*  wa = W  + (size_t)(jbase + srow) * TOTAL + i0 + shalf * 16;
  const ushort* gb = Gt + (size_t)(bbase + srow) * TOTAL + i0 + shalf * 16;

  for (int kk = 0; kk < ilen; kk += 32) {
    __syncthreads();
    { // A: load 16 f32, convert to 16 bf16, write 2 swizzled 16B chunks
      const float* p = wa + kk;
      float4 v0 = *(const float4*)p;
      float4 v1 = *(const float4*)(p + 4);
      float4 v2 = *(const float4*)(p + 8);
      float4 v3 = *(const float4*)(p + 12);
      uint4 p0, p1;
      p0.x = pack2(v0.x, v0.y); p0.y = pack2(v0.z, v0.w);
      p0.z = pack2(v1.x, v1.y); p0.w = pack2(v1.z, v1.w);
      p1.x = pack2(v2.x, v2.y); p1.y = pack2(v2.z, v2.w);
      p1.z = pack2(v3.x, v3.y); p1.w = pack2(v3.z, v3.w);
      Al[srow][(shalf * 2) ^ ssw]     = p0;
      Al[srow][(shalf * 2 + 1) ^ ssw] = p1;
      // B: already bf16, 2 x 16B straight through
      const uint4* q = (const uint4*)(gb + kk);
      Bl[srow][(shalf * 2) ^ ssw]     = q[0];
      Bl[srow][(shalf * 2 + 1) ^ ssw] = q[1];
    }
    __syncthreads();
    short8 af[4], bf[4];
#pragma unroll
    for (int m = 0; m < 4; m++)
      af[m] = *(const short8*)&Al[wm * 64 + m * 16 + rl][rdc];
#pragma unroll
    for (int n = 0; n < 4; n++)
      bf[n] = *(const short8*)&Bl[wn * 64 + n * 16 + rl][rdc];
#pragma unroll
    for (int m = 0; m < 4; m++)
#pragma unroll
      for (int n = 0; n < 4; n++)
        acc[m][n] = __builtin_amdgcn_mfma_f32_16x16x32_bf16(af[m], bf[n], acc[m][n], 0, 0, 0);
  }

  // epilogue: D frag is col=lane&15 (b), row=(lane>>4)*4+q (j)
#pragma unroll
  for (int m = 0; m < 4; m++) {
    int jr = jbase + wm * 64 + m * 16 + kh * 4;
#pragma unroll
    for (int n = 0; n < 4; n++) {
      int bc = bbase + wn * 64 + n * 16 + rl;
      float* cp = C + (size_t)jr * BATCH + bc;
#pragma unroll
      for (int q = 0; q < 4; q++) {
        float* pp = cp + (size_t)q * BATCH;
        if (init) *pp = acc[m][n][q];
        else      *pp += acc[m][n][q];
      }
    }
  }
}

// Sequential solve of one 128-node diagonal block, all 512 chains. f32 exact.
// 16 WGs x 256 threads; 8 lanes per batch (t&7), 32 batches/WG.
// Lane l owns nodes [16l,16l+16) (scatter-form accumulators).
__global__ void solve_block(const float* __restrict__ W, ushort* __restrict__ Gt,
                            const float* __restrict__ C, float* __restrict__ Hf,
                            int kblk) {
  __shared__ float Wt[NB][NB]; // Wt[i][swz(j)] = W[j0+j][IN_SIZE+j0+i]
  int j0 = kblk * NB;
  int t = threadIdx.x;
  int l = t & 7, g = t >> 3;
  int b = blockIdx.x * 32 + g;

  { // stage + transpose diag weight block, column-swizzled
    int j = t & 127, half = t >> 7;
    int pj = j ^ (((j >> 5) & 3) << 2);
    const float* wr = W + (size_t)(j0 + j) * TOTAL + IN_SIZE + j0 + half * 64;
#pragma unroll
    for (int q = 0; q < 64; q += 4) {
      float4 v = *(const float4*)(wr + q);
      int i = half * 64 + q;
      Wt[i + 0][pj] = v.x; Wt[i + 1][pj] = v.y; Wt[i + 2][pj] = v.z; Wt[i + 3][pj] = v.w;
    }
  }
  __syncthreads();

  float acc[16], hown[16];
  {
    const float* cb = C + (size_t)(j0 + l * 16) * BATCH + b;
#pragma unroll
    for (int m = 0; m < 16; m++) acc[m] = cb[(size_t)m * BATCH];
  }

  for (int r = 0; r < 8; r++) {
#pragma unroll
    for (int jj = 0; jj < 16; jj++) {
      int i = r * 16 + jj;
      float s = __shfl(acc[jj], r, 8);
      float h = fast_tanh(s);
      if (l == r) hown[jj] = h;
      const float* wrow = &Wt[i][0];
#pragma unroll
      for (int c = 0; c < 4; c++) {
        int col = l * 16 + c * 4;
        int pc = col ^ (((col >> 5) & 3) << 2);
        float4 wv = *(const float4*)(wrow + pc);
        // dead accumulators (already-solved nodes) absorb harmless garbage
        acc[c * 4 + 0] += h * wv.x;
        acc[c * 4 + 1] += h * wv.y;
        acc[c * 4 + 2] += h * wv.z;
        acc[c * 4 + 3] += h * wv.w;
      }
    }
  }

  { // publish h: 16 contiguous bf16 (32 B) per lane into Gt[b][...]
    ushort* gp = Gt + (size_t)b * TOTAL + IN_SIZE + j0 + l * 16;
    uint4 o0, o1;
    o0.x = pack2(hown[0],  hown[1]);  o0.y = pack2(hown[2],  hown[3]);
    o0.z = pack2(hown[4],  hown[5]);  o0.w = pack2(hown[6],  hown[7]);
    o1.x = pack2(hown[8],  hown[9]);  o1.y = pack2(hown[10], hown[11]);
    o1.z = pack2(hown[12], hown[13]); o1.w = pack2(hown[14], hown[15]);
    ((uint4*)gp)[0] = o0;
    ((uint4*)gp)[1] = o1;
  }
  if (kblk == NBLK - 1) { // last block = the 128 output nodes: keep exact f32
#pragma unroll
    for (int m = 0; m < 16; m++) Hf[(size_t)(l * 16 + m) * BATCH + b] = hown[m];
  }
}

// out[b][o] = sigmoid(Hf[o][b])
__global__ void out_sigmoid(const float* __restrict__ Hf, float* __restrict__ out) {
  int idx = blockIdx.x * 256 + threadIdx.x; // 65536
  int o = idx & 127, b = idx >> 7;
  float v = Hf[(size_t)o * BATCH + b];
  out[(size_t)b * OUTSZ + o] =
      __builtin_amdgcn_rcpf(1.0f + __builtin_amdgcn_exp2f(-v * 1.4426950408889634f));
}

extern "C" void kernel_launch(void* const* d_in, const int* in_sizes, int n_in,
                              void* d_out, int out_size, void* d_ws, size_t ws_size,
                              hipStream_t stream) {
  const float* x = (const float*)d_in[0];
  const float* W = (const float*)d_in[1];
  float* out = (float*)d_out;

  // workspace: Gt bf16 [512][5248] (10.75 MB) | C f32 [4224][512] (8.65 MB) | Hf f32 [128][512]
  ushort* Gt = (ushort*)d_ws;
  float* C   = (float*)((char*)d_ws + (size_t)BATCH * TOTAL * sizeof(ushort));
  float* Hf  = C + (size_t)N_NODES * BATCH;

  hipLaunchKernelGGL(conv_x, dim3(256), dim3(256), 0, stream, x, Gt);
  // init: C = W[:, :1024] . x^T (all 33 j-blocks)
  hipLaunchKernelGGL(gemm_bf16, dim3(NBLK, 4), dim3(256), 0, stream,
                     W, Gt, C, 0, IN_SIZE, 0, 1);
  for (int k = 0; k < NBLK; k++) {
    hipLaunchKernelGGL(solve_block, dim3(16), dim3(256), 0, stream, W, Gt, C, Hf, k);
    if (k < NBLK - 1) {
      // scatter block k's h into all future C columns (blocks k+1..32)
      hipLaunchKernelGGL(gemm_bf16, dim3(NBLK - 1 - k, 4), dim3(256), 0, stream,
                         W, Gt, C, IN_SIZE + k * NB, NB, (k + 1) * NB, 0);
    }
  }
  hipLaunchKernelGGL(out_sigmoid, dim3(256), dim3(256), 0, stream, Hf, out);
}